// Round 2
// baseline (481.452 us; speedup 1.0000x reference)
//
#include <hip/hip_runtime.h>
#include <hip/hip_bf16.h>

// CausalLinearAttention — bf16-MFMA, 3-pass segment-parallel scan.
// N=4, L=8192, H=16, E=D=64. This revision:
//  * raw lgkm-only barriers (s_waitcnt lgkmcnt(0) + s_barrier): global loads
//    and out-stores survive across barriers (no vmcnt(0) drain per chunk).
//  * pass1: 2-deep register prefetch + double-buffered LDS, 1 barrier/chunk;
//    ksum from f32 staging regs (shuffle-reduced at end, no in-loop LDS pass).
//  * pass3: V load issued at phase-A top, staged in phase C (T14 split);
//    out-stores no longer drained at B4.

#define Nn   4
#define Ll   8192
#define Hh   16
#define NHh  64
#define CCH  64          // chunk size (positions)
#define LDB  72          // bf16 LDS row stride: 144 B, 16B-multiple
#define SLOT 4160        // per-(nh,seg) ws slot: 4096 state + 64 ksum floats
#define EPSF 1e-6f

typedef __attribute__((ext_vector_type(8))) short short8;   // 8 bf16 = 4 VGPRs
typedef __attribute__((ext_vector_type(4))) float floatx4;  // MFMA accumulator

__device__ __forceinline__ float elu1(float x) {
  return x > 0.f ? x + 1.f : __expf(x);
}

__device__ __forceinline__ float4 elu4(float4 v) {
  v.x = elu1(v.x); v.y = elu1(v.y); v.z = elu1(v.z); v.w = elu1(v.w);
  return v;
}

__device__ __forceinline__ floatx4 mfma16(short8 a, short8 b, floatx4 c) {
  return __builtin_amdgcn_mfma_f32_16x16x32_bf16(a, b, c, 0, 0, 0);
}

// lgkm-only barrier: my ds ops complete, then block-sync. vmcnt NOT drained,
// so prefetched global loads / pending global stores stay in flight.
// 0xc07f = vmcnt(63) expcnt(7) lgkmcnt(0).
__device__ __forceinline__ void bar_lgkm() {
  __builtin_amdgcn_s_waitcnt(0xc07f);
  __builtin_amdgcn_s_barrier();
  __builtin_amdgcn_sched_barrier(0);  // no code motion across the barrier
}

// load an A/B fragment: row-major [row][k], 8 consecutive bf16 at
// k = kh*32 + quad*8
__device__ __forceinline__ short8 frag_ld(const __hip_bfloat16* base, int row,
                                          int kh, int quad) {
  return *(const short8*)(base + row * LDB + kh * 32 + quad * 8);
}

// pack 4 floats -> 4 bf16, single 8-byte LDS write (dst must be 8B-aligned)
__device__ __forceinline__ void st4bf(__hip_bfloat16* dst, float a, float b,
                                      float c, float d) {
  union { __hip_bfloat16 h[4]; uint2 u; } pk;
  pk.h[0] = __float2bfloat16(a); pk.h[1] = __float2bfloat16(b);
  pk.h[2] = __float2bfloat16(c); pk.h[3] = __float2bfloat16(d);
  *(uint2*)dst = pk.u;
}

__device__ __forceinline__ float bf2f(short s) {
  union { unsigned u; float f; } cv;
  cv.u = ((unsigned)(unsigned short)s) << 16;
  return cv.f;
}

__device__ __forceinline__ float sum8bf(short8 v) {
  float s = 0.f;
#pragma unroll
  for (int i = 0; i < 8; ++i) s += bf2f(v[i]);
  return s;
}

// ---------------------------------------------------------------- pass 1
// per-(nh,seg): partial S^T = V^T K (64x64) and ksum (64), written to ws.
// 2-deep pipelined: regs hold chunks c+1,c+2 in flight; LDS double-buffered.
__global__ __launch_bounds__(256, 4) void la_pass1(
    const float* __restrict__ Kg, const float* __restrict__ Vg,
    float* __restrict__ ws, int G, int Lseg) {
  const int bid = blockIdx.x;
  const int nh = bid / G, g = bid % G;
  const int n = nh / Hh, h = nh % Hh;
  const int t = threadIdx.x;
  const int wave = t >> 6, lane = t & 63, m = lane & 15, quad = lane >> 4;
  const int jr0 = m * 4;                   // 4x4-block transpose: source rows
  const int er0 = wave * 16 + quad * 4;    // dest rows (e)

  __shared__ __hip_bfloat16 Kt[2][64 * LDB];  // K^T [e][j], double-buffered
  __shared__ __hip_bfloat16 Vt[2][64 * LDB];  // V^T [d][j]

  floatx4 Sacc[4];  // S^T tiles: rows d = 16*wave+quad*4+r, cols e = 16*b+m
  const floatx4 z4 = {0.f, 0.f, 0.f, 0.f};
#pragma unroll
  for (int b = 0; b < 4; ++b) Sacc[b] = z4;
  float kpriv[4] = {0.f, 0.f, 0.f, 0.f};  // ksum partials for e = er0+i

  const int nchunk = Lseg / CCH;  // >= 8, even

#define P1_LOAD(KR, VR, c_) do { \
    const size_t gb_ = \
        ((size_t)((n * Ll + g * Lseg + (c_) * CCH + jr0) * Hh + h)) * 64 + er0; \
    KR[0] = *(const float4*)(Kg + gb_);        \
    KR[1] = *(const float4*)(Kg + gb_ + 1024); \
    KR[2] = *(const float4*)(Kg + gb_ + 2048); \
    KR[3] = *(const float4*)(Kg + gb_ + 3072); \
    VR[0] = *(const float4*)(Vg + gb_);        \
    VR[1] = *(const float4*)(Vg + gb_ + 1024); \
    VR[2] = *(const float4*)(Vg + gb_ + 2048); \
    VR[3] = *(const float4*)(Vg + gb_ + 3072); \
  } while (0)

#define P1_STAGE(KR, VR, p_) do { \
    float4 e0 = elu4(KR[0]), e1 = elu4(KR[1]), e2 = elu4(KR[2]), e3 = elu4(KR[3]); \
    kpriv[0] += e0.x + e1.x + e2.x + e3.x; \
    kpriv[1] += e0.y + e1.y + e2.y + e3.y; \
    kpriv[2] += e0.z + e1.z + e2.z + e3.z; \
    kpriv[3] += e0.w + e1.w + e2.w + e3.w; \
    __hip_bfloat16* kt_ = Kt[p_]; __hip_bfloat16* vt_ = Vt[p_]; \
    st4bf(&kt_[(er0 + 0) * LDB + jr0], e0.x, e1.x, e2.x, e3.x); \
    st4bf(&kt_[(er0 + 1) * LDB + jr0], e0.y, e1.y, e2.y, e3.y); \
    st4bf(&kt_[(er0 + 2) * LDB + jr0], e0.z, e1.z, e2.z, e3.z); \
    st4bf(&kt_[(er0 + 3) * LDB + jr0], e0.w, e1.w, e2.w, e3.w); \
    st4bf(&vt_[(er0 + 0) * LDB + jr0], VR[0].x, VR[1].x, VR[2].x, VR[3].x); \
    st4bf(&vt_[(er0 + 1) * LDB + jr0], VR[0].y, VR[1].y, VR[2].y, VR[3].y); \
    st4bf(&vt_[(er0 + 2) * LDB + jr0], VR[0].z, VR[1].z, VR[2].z, VR[3].z); \
    st4bf(&vt_[(er0 + 3) * LDB + jr0], VR[0].w, VR[1].w, VR[2].w, VR[3].w); \
  } while (0)

#define P1_MFMA(p_) do { \
    const short8 a0 = frag_ld(Vt[p_], 16 * wave + m, 0, quad); \
    const short8 a1 = frag_ld(Vt[p_], 16 * wave + m, 1, quad); \
    __builtin_amdgcn_s_setprio(1); \
    _Pragma("unroll") \
    for (int b = 0; b < 4; ++b) { \
      Sacc[b] = mfma16(a0, frag_ld(Kt[p_], 16 * b + m, 0, quad), Sacc[b]); \
      Sacc[b] = mfma16(a1, frag_ld(Kt[p_], 16 * b + m, 1, quad), Sacc[b]); \
    } \
    __builtin_amdgcn_s_setprio(0); \
  } while (0)

  float4 ka[4], va[4], kb[4], vb[4];
  P1_LOAD(ka, va, 0);
  P1_LOAD(kb, vb, 1);
  P1_STAGE(ka, va, 0);
  for (int c = 0; c < nchunk; c += 2) {
    if (c + 2 < nchunk) P1_LOAD(ka, va, c + 2);   // in flight across 2 barriers
    bar_lgkm();                                   // buf0 (chunk c) visible
    P1_MFMA(0);
    P1_STAGE(kb, vb, 1);                          // waits chunk c+1 loads
    if (c + 3 < nchunk) P1_LOAD(kb, vb, c + 3);
    bar_lgkm();                                   // buf1 (chunk c+1) visible
    P1_MFMA(1);
    if (c + 2 < nchunk) P1_STAGE(ka, va, 0);      // waits chunk c+2 loads
  }
#undef P1_LOAD
#undef P1_STAGE
#undef P1_MFMA

  // reduce ksum partials over the 16 m-lanes (same (wave,quad) -> same e's)
#pragma unroll
  for (int i = 0; i < 4; ++i) {
    kpriv[i] += __shfl_xor(kpriv[i], 1);
    kpriv[i] += __shfl_xor(kpriv[i], 2);
    kpriv[i] += __shfl_xor(kpriv[i], 4);
    kpriv[i] += __shfl_xor(kpriv[i], 8);
  }
  const size_t slot = (size_t)bid * SLOT;
#pragma unroll
  for (int b = 0; b < 4; ++b)
#pragma unroll
    for (int r = 0; r < 4; ++r) {
      const int d = 16 * wave + quad * 4 + r, e = 16 * b + m;
      ws[slot + d * 64 + e] = Sacc[b][r];
    }
  if (m == 0)
#pragma unroll
    for (int i = 0; i < 4; ++i) ws[slot + 4096 + er0 + i] = kpriv[i];
}

// ---------------------------------------------------------------- pass 2
// exclusive scan over segments; one element per thread, NHh*17 blocks.
__global__ __launch_bounds__(256) void la_pass2(float* __restrict__ ws, int G) {
  const int nh = blockIdx.x / 17, part = blockIdx.x % 17;
  const int idx = part * 256 + threadIdx.x;
  if (idx >= SLOT) return;
  float run = 0.f;
  for (int g = 0; g < G; ++g) {
    const size_t base = (size_t)(nh * G + g) * SLOT;
    const float cur = ws[base + idx];
    ws[base + idx] = run;
    run += cur;
  }
}

// ---------------------------------------------------------------- pass 3
__global__ __launch_bounds__(256, 4) void la_pass3(
    const float* __restrict__ Qg, const float* __restrict__ Kg,
    const float* __restrict__ Vg, const float* __restrict__ ws,
    float* __restrict__ out, int G, int Lseg, int has_prefix) {
  const int bid = blockIdx.x;
  const int nh = bid / G, g = bid % G;
  const int n = nh / Hh, h = nh % Hh;
  const int t = threadIdx.x;
  const int wave = t >> 6, lane = t & 63, m = lane & 15, quad = lane >> 4;
  const int row = t >> 2, q4 = t & 3;      // row-major staging coords
  const int jr0 = m * 4;                   // V 4x4-block transposed staging
  const int er0 = wave * 16 + quad * 4;

  __shared__ __hip_bfloat16 QPb[64 * LDB];  // Q [i][e], then masked P [i][j]
  __shared__ __hip_bfloat16 Kb [64 * LDB];  // K [j][e], then S^T snapshot [d][e]
  __shared__ __hip_bfloat16 Ktb[64 * LDB];  // K^T [e][j]
  __shared__ __hip_bfloat16 Vtb[64 * LDB];  // V^T [d][j]
  __shared__ float ksum[64];
  __shared__ float kpart[4][64];

  const size_t slot = (size_t)bid * SLOT;
  floatx4 Sacc[4];  // persistent S^T: rows d = 16*wave+quad*4+r, cols e = 16*b+m
  const floatx4 z4 = {0.f, 0.f, 0.f, 0.f};
#pragma unroll
  for (int b = 0; b < 4; ++b) {
    Sacc[b] = z4;
    if (has_prefix) {
#pragma unroll
      for (int r = 0; r < 4; ++r)
        Sacc[b][r] = ws[slot + (16 * wave + quad * 4 + r) * 64 + 16 * b + m];
    }
  }
  if (t < 64) ksum[t] = has_prefix ? ws[slot + 4096 + t] : 0.f;

  const int nchunk = Lseg / CCH;
  for (int c = 0; c < nchunk; ++c) {
    const int lbase = g * Lseg + c * CCH;
    // ---- phase A: issue Q,K,V loads; stage Q,K (V deferred to phase C)
    const size_t gbr = ((size_t)((n * Ll + lbase + row) * Hh + h)) * 64;
    const size_t gbv = ((size_t)((n * Ll + lbase + jr0) * Hh + h)) * 64 + er0;
    float4 qr[4], kr[4];
#pragma unroll
    for (int u = 0; u < 4; ++u) {
      const int col = u * 16 + q4 * 4;
      qr[u] = *(const float4*)(Qg + gbr + col);
      kr[u] = *(const float4*)(Kg + gbr + col);
    }
    float4 vr0 = *(const float4*)(Vg + gbv);
    float4 vr1 = *(const float4*)(Vg + gbv + 1024);
    float4 vr2 = *(const float4*)(Vg + gbv + 2048);
    float4 vr3 = *(const float4*)(Vg + gbv + 3072);
#pragma unroll
    for (int u = 0; u < 4; ++u) {
      const int col = u * 16 + q4 * 4;
      float4 qv = elu4(qr[u]);
      float4 kv = elu4(kr[u]);
      st4bf(&QPb[row * LDB + col], qv.x, qv.y, qv.z, qv.w);
      st4bf(&Kb [row * LDB + col], kv.x, kv.y, kv.z, kv.w);
      Ktb[(col + 0) * LDB + row] = __float2bfloat16(kv.x);
      Ktb[(col + 1) * LDB + row] = __float2bfloat16(kv.y);
      Ktb[(col + 2) * LDB + row] = __float2bfloat16(kv.z);
      Ktb[(col + 3) * LDB + row] = __float2bfloat16(kv.w);
    }
    bar_lgkm();  // B1: Q,K tiles staged (V loads still in flight)

    // ---- phase B: m1 (sc = Q K^T) + denominator in registers
    const short8 qa0 = frag_ld(QPb, 16 * wave + m, 0, quad);
    const short8 qa1 = frag_ld(QPb, 16 * wave + m, 1, quad);
    floatx4 sc[4];
    __builtin_amdgcn_s_setprio(1);
#pragma unroll
    for (int b = 0; b < 4; ++b) {
      sc[b] = mfma16(qa0, frag_ld(Kb, 16 * b + m, 0, quad), z4);
      sc[b] = mfma16(qa1, frag_ld(Kb, 16 * b + m, 1, quad), sc[b]);
    }
    __builtin_amdgcn_s_setprio(0);
    // dden for row i' = 16*wave + m from register fragments:
    // qa0 covers e = quad*8..+7, qa1 covers e = 32+quad*8..+7
    float dpart = 0.f;
    {
      const float* ks0 = &ksum[quad * 8];        // broadcast reads
      const float* ks1 = &ksum[32 + quad * 8];
#pragma unroll
      for (int u = 0; u < 8; ++u) dpart += bf2f(qa0[u]) * ks0[u];
#pragma unroll
      for (int u = 0; u < 8; ++u) dpart += bf2f(qa1[u]) * ks1[u];
    }
    dpart += __shfl_xor(dpart, 16);
    dpart += __shfl_xor(dpart, 32);  // all lanes: full dden[16*wave + m]
    // rs[r] = sum_j masked sc; z[r] in registers
    float z[4];
#pragma unroll
    for (int r = 0; r < 4; ++r) {
      const int i = 16 * wave + quad * 4 + r;
      float rs = 0.f;
#pragma unroll
      for (int b = 0; b < 4; ++b) {
        const int j = 16 * b + m;
        rs += (j <= i) ? sc[b][r] : 0.f;
      }
      rs += __shfl_xor(rs, 1);
      rs += __shfl_xor(rs, 2);
      rs += __shfl_xor(rs, 4);
      rs += __shfl_xor(rs, 8);
      const float den = __shfl(dpart, quad * 4 + r);  // lane m' = quad*4+r
      z[r] = 1.f / (den + rs + EPSF);
    }
    bar_lgkm();  // B2: Q/Kb reads done; QPb->P, Kb->snapshot next

    // ---- phase C: masked P -> QPb; S^T snapshot -> Kb; stage V -> Vtb
#pragma unroll
    for (int b = 0; b < 4; ++b)
#pragma unroll
      for (int r = 0; r < 4; ++r) {
        const int i = 16 * wave + quad * 4 + r, j = 16 * b + m;
        QPb[i * LDB + j] = __float2bfloat16(j <= i ? sc[b][r] : 0.f);
        Kb[i * LDB + j] = __float2bfloat16(Sacc[b][r]);  // rows d, cols e
      }
    st4bf(&Vtb[(er0 + 0) * LDB + jr0], vr0.x, vr1.x, vr2.x, vr3.x);
    st4bf(&Vtb[(er0 + 1) * LDB + jr0], vr0.y, vr1.y, vr2.y, vr3.y);
    st4bf(&Vtb[(er0 + 2) * LDB + jr0], vr0.z, vr1.z, vr2.z, vr3.z);
    st4bf(&Vtb[(er0 + 3) * LDB + jr0], vr0.w, vr1.w, vr2.w, vr3.w);
    bar_lgkm();  // B3: P + snapshot + V visible

    // ---- phase D: m2 (Q S_prev) + m3 (P V) + m4 (S += V^T K)
    const short8 pa0 = frag_ld(QPb, 16 * wave + m, 0, quad);
    const short8 pa1 = frag_ld(QPb, 16 * wave + m, 1, quad);
    const short8 va0 = frag_ld(Vtb, 16 * wave + m, 0, quad);
    const short8 va1 = frag_ld(Vtb, 16 * wave + m, 1, quad);
    floatx4 O[4];
    __builtin_amdgcn_s_setprio(1);
#pragma unroll
    for (int b = 0; b < 4; ++b) {
      O[b] = mfma16(qa0, frag_ld(Kb, 16 * b + m, 0, quad), z4);
      O[b] = mfma16(qa1, frag_ld(Kb, 16 * b + m, 1, quad), O[b]);
      O[b] = mfma16(pa0, frag_ld(Vtb, 16 * b + m, 0, quad), O[b]);
      O[b] = mfma16(pa1, frag_ld(Vtb, 16 * b + m, 1, quad), O[b]);
      Sacc[b] = mfma16(va0, frag_ld(Ktb, 16 * b + m, 0, quad), Sacc[b]);
      Sacc[b] = mfma16(va1, frag_ld(Ktb, 16 * b + m, 1, quad), Sacc[b]);
    }
    __builtin_amdgcn_s_setprio(0);
    {  // ksum partials for next chunk
      const short8 x0 = *(const short8*)(&Ktb[lane * LDB + wave * 16]);
      const short8 x1 = *(const short8*)(&Ktb[lane * LDB + wave * 16 + 8]);
      kpart[wave][lane] = sum8bf(x0) + sum8bf(x1);
    }
    const size_t ob = ((size_t)((n * Ll + lbase) * Hh + h)) * 64;
#pragma unroll
    for (int r = 0; r < 4; ++r) {
      const int i = 16 * wave + quad * 4 + r;
#pragma unroll
      for (int b = 0; b < 4; ++b)
        out[ob + (size_t)i * (Hh * 64) + 16 * b + m] = O[b][r] * z[r];
    }
    bar_lgkm();  // B4: all LDS reads of this chunk done (stores NOT drained)
    if (t < 64)
      ksum[t] += kpart[0][t] + kpart[1][t] + kpart[2][t] + kpart[3][t];
  }
}

// ---------------------------------------------------------------- launch
extern "C" void kernel_launch(void* const* d_in, const int* in_sizes, int n_in,
                              void* d_out, int out_size, void* d_ws, size_t ws_size,
                              hipStream_t stream) {
  (void)in_sizes; (void)n_in; (void)out_size;
  const float* Qg = (const float*)d_in[0];
  const float* Kg = (const float*)d_in[1];
  const float* Vg = (const float*)d_in[2];
  float* out = (float*)d_out;
  float* ws = (float*)d_ws;

  const size_t per_seg = (size_t)NHh * SLOT * sizeof(float);
  int G = 1;
  if (ws_size >= 16 * per_seg) G = 16;
  else if (ws_size >= 8 * per_seg) G = 8;
  else if (ws_size >= 4 * per_seg) G = 4;
  else if (ws_size >= 2 * per_seg) G = 2;
  const int Lseg = Ll / G;

  if (G > 1) {
    la_pass1<<<NHh * G, 256, 0, stream>>>(Kg, Vg, ws, G, Lseg);
    la_pass2<<<NHh * 17, 256, 0, stream>>>(ws, G);
  }
  la_pass3<<<NHh * G, 256, 0, stream>>>(Qg, Kg, Vg, ws, out, G, Lseg, G > 1 ? 1 : 0);
}